// Round 1
// baseline (234.853 us; speedup 1.0000x reference)
//
#include <hip/hip_runtime.h>

#define B_ 16
#define N_ 4096
#define F_ 8
#define H_ 64
#define C_ 256
#define FH 512      // F_*H_
#define CAP 256     // max nodes per segment (binomial mean 16; 256 is unreachable)

// ---------------------------------------------------------------------------
// Kernel 1: scores[b*N+n] = (sum_{f,h} x[b,n,f,h]*W[h]) / F + bias
// One wave64 per node. Lane l covers (f0, h:hq..hq+3) and (f0+4, same h quad)
// => two fully-coalesced float4 loads (1 KB per wave per instruction).
// ---------------------------------------------------------------------------
__global__ __launch_bounds__(256) void scores_kernel(
    const float* __restrict__ x, const float* __restrict__ W,
    const float* __restrict__ bias, float* __restrict__ scores)
{
    int gtid = blockIdx.x * 256 + threadIdx.x;
    int node = gtid >> 6;             // [0, B_*N_)
    int lane = gtid & 63;
    const float* xp = x + (size_t)node * FH;
    int f0 = lane >> 4;               // 0..3
    int hq = (lane & 15) * 4;         // 0,4,...,60
    float4 w4 = *(const float4*)(W + hq);
    float4 a  = *(const float4*)(xp + f0 * H_ + hq);
    float4 b4 = *(const float4*)(xp + (f0 + 4) * H_ + hq);
    float partial = (a.x + b4.x) * w4.x + (a.y + b4.y) * w4.y
                  + (a.z + b4.z) * w4.z + (a.w + b4.w) * w4.w;
#pragma unroll
    for (int off = 32; off > 0; off >>= 1)
        partial += __shfl_xor(partial, off, 64);
    if (lane == 0)
        scores[node] = partial * (1.0f / F_) + bias[0];
}

// ---------------------------------------------------------------------------
// Kernel 2: per-(b, segment) softmax weights. One block per batch.
// LDS atomicMax on monotone uint-mapped floats for segment max,
// LDS atomicAdd(float) for the denominator.
// ---------------------------------------------------------------------------
__device__ __forceinline__ unsigned fmap(float f) {
    unsigned u = __float_as_uint(f);
    return (u & 0x80000000u) ? ~u : (u | 0x80000000u);
}
__device__ __forceinline__ float funmap(unsigned u) {
    return (u & 0x80000000u) ? __uint_as_float(u ^ 0x80000000u)
                             : __uint_as_float(~u);
}

__global__ __launch_bounds__(256) void softmax_kernel(
    const float* __restrict__ scores, const int* __restrict__ seg,
    float* __restrict__ w)
{
    int b = blockIdx.x;
    int t = threadIdx.x;
    __shared__ unsigned smax[C_];
    __shared__ float ssum[C_];
    smax[t] = 0u;       // below fmap(-inf) = 0x007FFFFF
    ssum[t] = 0.0f;
    __syncthreads();

    float sc[N_ / 256];
    int   sg[N_ / 256];
#pragma unroll
    for (int k = 0; k < N_ / 256; k++) {
        int n = t + k * 256;
        sg[k] = seg[n];
        sc[k] = scores[b * N_ + n];
        atomicMax(&smax[sg[k]], fmap(sc[k]));
    }
    __syncthreads();

    float ev[N_ / 256];
#pragma unroll
    for (int k = 0; k < N_ / 256; k++) {
        float m = funmap(smax[sg[k]]);
        ev[k] = __expf(sc[k] - m);
        atomicAdd(&ssum[sg[k]], ev[k]);
    }
    __syncthreads();

#pragma unroll
    for (int k = 0; k < N_ / 256; k++) {
        int n = t + k * 256;
        w[b * N_ + n] = ev[k] / ssum[sg[k]];
    }
}

// ---------------------------------------------------------------------------
// Kernel 3: pooled[b,c,f,h] = sum_{n: seg[n]==c} w[b,n] * x[b,n,f,h]
// One block of 128 threads per (b,c). Phase 1: compact the segment's node
// list into LDS. Phase 2: thread t owns float4 lane t of the 512-wide
// feature vector, accumulates over the list with coalesced float4 loads.
// ---------------------------------------------------------------------------
__global__ __launch_bounds__(128) void pool_kernel(
    const float* __restrict__ x, const float* __restrict__ w,
    const int* __restrict__ seg, float* __restrict__ out)
{
    int b = blockIdx.x >> 8;      // / C_
    int c = blockIdx.x & (C_ - 1);
    int t = threadIdx.x;

    __shared__ int   list[CAP];
    __shared__ float wl[CAP];
    __shared__ int   cnt;
    if (t == 0) cnt = 0;
    __syncthreads();

#pragma unroll
    for (int k = 0; k < N_ / 128; k++) {
        int n = t + k * 128;
        if (seg[n] == c) {
            int pos = atomicAdd(&cnt, 1);
            if (pos < CAP) {
                list[pos] = n;
                wl[pos]   = w[b * N_ + n];
            }
        }
    }
    __syncthreads();

    int m = cnt;
    if (m > CAP) m = CAP;

    const float4* x4 = (const float4*)x;
    float4 acc0 = {0, 0, 0, 0}, acc1 = {0, 0, 0, 0};
    float4 acc2 = {0, 0, 0, 0}, acc3 = {0, 0, 0, 0};

    int i = 0;
    for (; i + 4 <= m; i += 4) {
        int n0 = list[i], n1 = list[i + 1], n2 = list[i + 2], n3 = list[i + 3];
        float w0 = wl[i], w1 = wl[i + 1], w2 = wl[i + 2], w3 = wl[i + 3];
        float4 v0 = x4[((size_t)(b * N_ + n0)) * (FH / 4) + t];
        float4 v1 = x4[((size_t)(b * N_ + n1)) * (FH / 4) + t];
        float4 v2 = x4[((size_t)(b * N_ + n2)) * (FH / 4) + t];
        float4 v3 = x4[((size_t)(b * N_ + n3)) * (FH / 4) + t];
        acc0.x += w0 * v0.x; acc0.y += w0 * v0.y; acc0.z += w0 * v0.z; acc0.w += w0 * v0.w;
        acc1.x += w1 * v1.x; acc1.y += w1 * v1.y; acc1.z += w1 * v1.z; acc1.w += w1 * v1.w;
        acc2.x += w2 * v2.x; acc2.y += w2 * v2.y; acc2.z += w2 * v2.z; acc2.w += w2 * v2.w;
        acc3.x += w3 * v3.x; acc3.y += w3 * v3.y; acc3.z += w3 * v3.z; acc3.w += w3 * v3.w;
    }
    for (; i < m; i++) {
        int n0 = list[i];
        float w0 = wl[i];
        float4 v0 = x4[((size_t)(b * N_ + n0)) * (FH / 4) + t];
        acc0.x += w0 * v0.x; acc0.y += w0 * v0.y; acc0.z += w0 * v0.z; acc0.w += w0 * v0.w;
    }

    float4 r;
    r.x = (acc0.x + acc1.x) + (acc2.x + acc3.x);
    r.y = (acc0.y + acc1.y) + (acc2.y + acc3.y);
    r.z = (acc0.z + acc1.z) + (acc2.z + acc3.z);
    r.w = (acc0.w + acc1.w) + (acc2.w + acc3.w);
    ((float4*)out)[((size_t)(b * C_ + c)) * (FH / 4) + t] = r;
}

// ---------------------------------------------------------------------------
extern "C" void kernel_launch(void* const* d_in, const int* in_sizes, int n_in,
                              void* d_out, int out_size, void* d_ws, size_t ws_size,
                              hipStream_t stream)
{
    const float* x    = (const float*)d_in[0];
    const float* W    = (const float*)d_in[1];
    const float* bias = (const float*)d_in[2];
    const int*   seg  = (const int*)d_in[3];
    float* out = (float*)d_out;

    float* scores = (float*)d_ws;          // B_*N_ floats
    float* w      = scores + B_ * N_;      // B_*N_ floats

    scores_kernel<<<B_ * N_ / 4, 256, 0, stream>>>(x, W, bias, scores);
    softmax_kernel<<<B_, 256, 0, stream>>>(scores, seg, w);
    pool_kernel<<<B_ * C_, 128, 0, stream>>>(x, w, seg, out);
}